// Round 17
// baseline (409.189 us; speedup 1.0000x reference)
//
#include <hip/hip_runtime.h>
#include <hip/hip_bf16.h>
#include <math.h>

#define N 4096
#define IN_FT 512
#define OUT_FT 512
#define COS_THR 0.5f
#define COS_K 10
#define EPSN 1e-12f
#define CAP 256          // max stored nnz per row/col (actual ~10)
#define NW (N / 32)      // bitmask words per row
#define CAP_C 128        // candidate slots per flagged row (fix path)
#define GAPWIN 2e-4f     // ambiguity window; bf16x3 error ~1.5e-5 + mirror ulp
#define CNB 32           // 128-blocks per side
#define T0 0.08f         // candidate threshold (data-checked, fallback-safe)
#define CAPT 192         // per-row candidate capacity (mean ~144, 4 sigma)

typedef short s16x8 __attribute__((ext_vector_type(8)));
typedef float f32x4 __attribute__((ext_vector_type(4)));

__device__ __forceinline__ unsigned short f2bf(float f) {
    unsigned u = __float_as_uint(f);
    u += 0x7fff + ((u >> 16) & 1);          // RNE to bf16
    return (unsigned short)(u >> 16);
}
__device__ __forceinline__ float bf2f(unsigned short h) {
    return __uint_as_float(((unsigned)h) << 16);
}
__device__ __forceinline__ void gload_lds16(const void* g, void* l) {
    __builtin_amdgcn_global_load_lds(
        (const __attribute__((address_space(1))) void*)g,
        (__attribute__((address_space(3))) void*)l, 16, 0, 0);
}

// ---------- row-normalize: bf16 hi/lo of xn + norms; zero ccnt/fbflag ----------
__global__ __launch_bounds__(256) void rownorm_k(const float* __restrict__ x,
                                                 unsigned short* __restrict__ xnh,
                                                 unsigned short* __restrict__ xnl,
                                                 float* __restrict__ norminv,
                                                 float* __restrict__ nrm,
                                                 int* __restrict__ ccnt,
                                                 int* __restrict__ fbflag) {
    int row = blockIdx.x;
    const float* xr = x + (size_t)row * IN_FT;
    float s = 0.f;
    for (int j = threadIdx.x; j < IN_FT; j += 256) { float v = xr[j]; s += v * v; }
    __shared__ float red[256];
    red[threadIdx.x] = s; __syncthreads();
    for (int off = 128; off > 0; off >>= 1) {
        if (threadIdx.x < off) red[threadIdx.x] += red[threadIdx.x + off];
        __syncthreads();
    }
    float nr = fmaxf(sqrtf(red[0]), 1e-12f);
    float inv = 1.0f / nr;
    if (threadIdx.x == 0) { norminv[row] = inv; nrm[row] = nr; ccnt[row] = 0; fbflag[row] = 0; }
    for (int j = threadIdx.x; j < IN_FT; j += 256) {
        float v = xr[j] * inv;                 // same op the fix path replays
        unsigned short hi = f2bf(v);
        unsigned short lo = f2bf(v - bf2f(hi));
        xnh[(size_t)row * IN_FT + j] = hi;
        xnl[(size_t)row * IN_FT + j] = lo;
    }
}

// ---------- approx cos: bf16x3 MFMA, upper-tri + fused mirror + candidate emit ----------
// Emits every value > T0 to per-row lists (atomic counter: SET deterministic,
// order not -> all consumers use (value desc, index asc) total order, which is
// order-invariant). Dense C still written (fallback path needs it).
__global__ __launch_bounds__(256) void cos_gemm_k(const unsigned short* __restrict__ xh,
                                                  const unsigned short* __restrict__ xl,
                                                  float* __restrict__ C,
                                                  int* __restrict__ ccnt,
                                                  float* __restrict__ cval,
                                                  int* __restrict__ cidx) {
    __shared__ __align__(16) unsigned short As[2][128 * 32];
    __shared__ __align__(16) unsigned short Bs[2][128 * 32];
    int bid = blockIdx.x;                      // 0 .. 527
    int t = (bid & 7) * 66 + (bid >> 3);       // XCD-chunked bijection
    int by = 0;
    while (t >= CNB - by) { t -= CNB - by; ++by; }
    int bx = by + t;                           // by <= bx
    int tid = threadIdx.x;
    int wave = tid >> 6, l = tid & 63;
    int bi = by * 128, bj = bx * 128;
    int wm = wave >> 1, wn = wave & 1;
    int lm0 = wm * 64, ln0 = wn * 64;
    int lr4 = l >> 2;
    int lc4s = (((l & 3) ^ ((l >> 3) & 3)) * 8);   // swizzled SOURCE chunk
    int lr = l & 15, lg = l >> 4;
    int kqs = (((l >> 4) ^ ((l >> 1) & 3)) * 8);   // swizzled read chunk
    f32x4 acc[4][4] = {};
    int buf = 0;
#pragma unroll
    for (int q = 0; q < 2; ++q) {
        int r0 = (wave + q * 4) * 16;
        gload_lds16(xh + (size_t)(bi + r0 + lr4) * IN_FT + lc4s, &As[0][r0 * 32]);
        gload_lds16(xh + (size_t)(bj + r0 + lr4) * IN_FT + lc4s, &Bs[0][r0 * 32]);
    }
    asm volatile("s_waitcnt vmcnt(0)" ::: "memory");
    __syncthreads();
    for (int kt = 0; kt < 48; ++kt) {
        if (kt + 1 < 48) {
            int p = (kt + 1) >> 4;
            int kc = ((kt + 1) & 15) * 32;
            const unsigned short* sa = (p == 2) ? xl : xh;
            const unsigned short* sb = (p == 1) ? xl : xh;
#pragma unroll
            for (int q = 0; q < 2; ++q) {
                int r0 = (wave + q * 4) * 16;
                gload_lds16(sa + (size_t)(bi + r0 + lr4) * IN_FT + kc + lc4s,
                            &As[buf ^ 1][r0 * 32]);
                gload_lds16(sb + (size_t)(bj + r0 + lr4) * IN_FT + kc + lc4s,
                            &Bs[buf ^ 1][r0 * 32]);
            }
        }
        s16x8 a[4], b[4];
#pragma unroll
        for (int mi = 0; mi < 4; ++mi)
            a[mi] = *(const s16x8*)&As[buf][(lm0 + mi * 16 + lr) * 32 + kqs];
#pragma unroll
        for (int ni = 0; ni < 4; ++ni)
            b[ni] = *(const s16x8*)&Bs[buf][(ln0 + ni * 16 + lr) * 32 + kqs];
#pragma unroll
        for (int mi = 0; mi < 4; ++mi)
#pragma unroll
            for (int ni = 0; ni < 4; ++ni)
                acc[mi][ni] = __builtin_amdgcn_mfma_f32_16x16x32_bf16(a[mi], b[ni], acc[mi][ni], 0, 0, 0);
        asm volatile("s_waitcnt vmcnt(0)" ::: "memory");
        __syncthreads();
        buf ^= 1;
    }
    // upper block store + candidate emission
#pragma unroll
    for (int mi = 0; mi < 4; ++mi)
#pragma unroll
        for (int r = 0; r < 4; ++r) {
            int m = bi + lm0 + mi * 16 + lg * 4 + r;
#pragma unroll
            for (int ni = 0; ni < 4; ++ni) {
                float val = acc[mi][ni][r];
                int n = bj + ln0 + ni * 16 + lr;
                C[(size_t)m * N + n] = val;
                if (val > T0) {
                    int p = atomicAdd(&ccnt[m], 1);
                    if (p < CAPT) {
                        cval[(size_t)m * CAPT + p] = val;
                        cidx[(size_t)m * CAPT + p] = n;
                    }
                }
            }
        }
    // mirrored store + candidate emission (values bit-identical: IEEE a*b==b*a)
    if (bx != by) {
#pragma unroll
        for (int ni = 0; ni < 4; ++ni) {
            int cc = bj + ln0 + ni * 16 + lr;
#pragma unroll
            for (int mi = 0; mi < 4; ++mi) {
                float4 s = make_float4(acc[mi][ni][0], acc[mi][ni][1],
                                       acc[mi][ni][2], acc[mi][ni][3]);
                *(float4*)&C[(size_t)cc * N + bi + lm0 + mi * 16 + lg * 4] = s;
#pragma unroll
                for (int r = 0; r < 4; ++r) {
                    float val = acc[mi][ni][r];
                    if (val > T0) {
                        int p = atomicAdd(&ccnt[cc], 1);
                        if (p < CAPT) {
                            cval[(size_t)cc * CAPT + p] = val;
                            cidx[(size_t)cc * CAPT + p] = bi + lm0 + mi * 16 + lg * 4 + r;
                        }
                    }
                }
            }
        }
    }
}

// ---------- fast top-k over candidate lists (order-invariant selection) ----------
// All mask-relevant values are > T0 (selection: v10 > T0; threshold: 0.5 > T0;
// window: guarded v10-GAPWIN > T0). Any violated assumption -> fbflag, return
// before writes; fallback kernel (r15 full path) handles that row from dense C.
__global__ __launch_bounds__(256) void topk_fast_k(const float* __restrict__ cval,
                                                   const int* __restrict__ cidx,
                                                   const int* __restrict__ ccnt,
                                                   const float* __restrict__ x,
                                                   const float* __restrict__ norminv,
                                                   unsigned* __restrict__ maskT,
                                                   const float* __restrict__ w2,
                                                   const float* __restrict__ Hmat,
                                                   int* __restrict__ rlist,
                                                   float* __restrict__ rval,
                                                   int* __restrict__ rcnt,
                                                   int* __restrict__ fbflag) {
    int row = blockIdx.x, tid = threadIdx.x;
    int lane = tid & 63, wid = tid >> 6;
    __shared__ int   win[10];
    __shared__ float v10s;
    __shared__ int   wred[4];
    __shared__ int   cjp[CAP_C];
    __shared__ int   cjj[CAP_C];
    __shared__ float exv[CAP_C];
    __shared__ unsigned char selw[CAP_C];
    __shared__ unsigned char candflag[CAPT];
    __shared__ unsigned ldsmask[NW];
    int Mc = ccnt[row];
    if (Mc < COS_K || Mc > CAPT) { if (tid == 0) fbflag[row] = 1; return; }
    // --- wave 0: top-10 over candidates, (value desc, index asc) total order ---
    if (wid == 0) {
        float cv[3]; int ci[3];
#pragma unroll
        for (int s = 0; s < 3; ++s) {
            int p = s * 64 + lane;
            bool ok = p < Mc;
            cv[s] = ok ? cval[(size_t)row * CAPT + p] : -INFINITY;
            ci[s] = ok ? cidx[(size_t)row * CAPT + p] : 0x7fffffff;
        }
        unsigned exm = 0;
        for (int t = 0; t < COS_K; ++t) {
            float best = -INFINITY; int bidx = 0x7fffffff;
#pragma unroll
            for (int s = 0; s < 3; ++s)
                if (!((exm >> s) & 1) &&
                    (cv[s] > best || (cv[s] == best && ci[s] < bidx))) { best = cv[s]; bidx = ci[s]; }
#pragma unroll
            for (int off = 32; off > 0; off >>= 1) {
                float v2 = __shfl_xor(best, off);
                int   i2 = __shfl_xor(bidx, off);
                if (v2 > best || (v2 == best && i2 < bidx)) { best = v2; bidx = i2; }
            }
#pragma unroll
            for (int s = 0; s < 3; ++s)       // indices unique -> owner marks
                if (ci[s] == bidx) exm |= 1u << s;
            if (lane == 0) { win[t] = bidx; if (t == COS_K - 1) v10s = best; }
        }
    }
    __syncthreads();
    float v10 = v10s;
    if (v10 - GAPWIN <= T0) { if (tid == 0) fbflag[row] = 1; return; }  // uniform
    bool valid = tid < Mc;
    float myv = 0.f; int myj = -1;
    if (valid) {
        myv = cval[(size_t)row * CAPT + tid];
        myj = cidx[(size_t)row * CAPT + tid];
    }
    bool isw = valid && ((myv > v10 - GAPWIN) || (fabsf(myv - COS_THR) < GAPWIN));
    unsigned long long wb = __ballot(isw);
    if (lane == 0) wred[wid] = __popcll(wb);
    __syncthreads();
    int Mw = wred[0] + wred[1] + wred[2] + wred[3];
    if (Mw > CAP_C) { if (tid == 0) fbflag[row] = 1; return; }          // uniform
    bool inwin = false;
    if (valid) {
#pragma unroll
        for (int t = 0; t < COS_K; ++t) if (win[t] == myj) inwin = true;
        candflag[tid] = ((myv > COS_THR) || inwin) ? 1 : 0;
    }
    bool amb = Mw > COS_K;     // window always contains the 10 selected
    if (amb) {
        int pb = isw ? 1 : 0;
        int scan = pb;
#pragma unroll
        for (int off = 1; off < 64; off <<= 1) {
            int nv = __shfl_up(scan, off);
            if (lane >= off) scan += nv;
        }
        int base = scan - pb;
        for (int w = 0; w < wid; ++w) base += wred[w];
        if (pb) cjp[base] = tid;
        __syncthreads();
        if (tid < Mw) {        // exact dots: identical serial ascending-k chain
            int j = cidx[(size_t)row * CAPT + cjp[tid]];
            cjj[tid] = j;
            float invr = norminv[row], invj = norminv[j];
            const float* xr = x + (size_t)row * IN_FT;
            const float* xj = x + (size_t)j * IN_FT;
            float acc = 0.f;
            for (int k = 0; k < IN_FT; ++k)
                acc = fmaf(xr[k] * invr, xj[k] * invj, acc);
            exv[tid] = acc;
        }
        __syncthreads();
        if (tid < Mw) {        // rank with identical comparator
            float vv = exv[tid]; int j = cjj[tid];
            int rank = 0;
            for (int m2 = 0; m2 < Mw; ++m2) {
                float v2 = exv[m2]; int j2 = cjj[m2];
                if (v2 > vv || (v2 == vv && j2 < j)) ++rank;
            }
            selw[tid] = (rank < COS_K) ? 1 : 0;
        }
        __syncthreads();
        if (tid < Mw)
            candflag[cjp[tid]] = ((exv[tid] > COS_THR) || selw[tid]) ? 1 : 0;
    }
    __syncthreads();
    // --- build row bitmask from flagged candidates ---
    if (tid < NW) ldsmask[tid] = 0;
    __syncthreads();
    if (valid && candflag[tid]) atomicOr(&ldsmask[myj >> 5], 1u << (myj & 31));
    __syncthreads();
    if (tid < NW) maskT[(size_t)tid * N + row] = ldsmask[tid];
    // --- row list (ascending j) via 128-thread word scan ---
    unsigned word = 0; int cnt = 0;
    if (tid < NW) { word = ldsmask[tid]; cnt = __popc(word); }
    int scan2 = cnt;
#pragma unroll
    for (int off = 1; off < 64; off <<= 1) {
        int nv = __shfl_up(scan2, off);
        if (lane >= off) scan2 += nv;
    }
    if (lane == 63) wred[wid] = scan2;     // waves 2,3 contribute 0
    __syncthreads();
    if (tid < NW) {
        int base2 = scan2 - cnt + (wid == 1 ? wred[0] : 0);
        unsigned m = word; int pos = base2;
        while (m) {
            int b = __builtin_ctz(m); m &= m - 1;
            int j = tid * 32 + b;
            if (pos < CAP) {
                size_t ofs = (size_t)row * N + j;
                rlist[(size_t)row * CAP + pos] = j;
                rval[(size_t)row * CAP + pos] = w2[ofs] * Hmat[ofs];
            }
            ++pos;
        }
    }
    if (tid == 0) {
        int tot = wred[0] + wred[1];
        rcnt[row] = tot < CAP ? tot : CAP;
    }
}

// ---------- fallback: r15 full path from dense cos (guarded, ~never runs) ----------
__global__ __launch_bounds__(256) void topk_fb_k(const int* __restrict__ fbflag,
                                                 const float* __restrict__ cosm,
                                                 const float* __restrict__ x,
                                                 const float* __restrict__ norminv,
                                                 unsigned* __restrict__ maskT,
                                                 const float* __restrict__ w2,
                                                 const float* __restrict__ Hmat,
                                                 int* __restrict__ rlist,
                                                 float* __restrict__ rval,
                                                 int* __restrict__ rcnt) {
    int row = blockIdx.x;
    if (!fbflag[row]) return;
    int tid = threadIdx.x;
    int lane = tid & 63, wid = tid >> 6;
    __shared__ float wv[4][10];
    __shared__ int   wi[4][10];
    __shared__ int   win[10];
    __shared__ float v10s;
    __shared__ int   wtot[4];
    __shared__ int   wamb[4];
    __shared__ int   cj[CAP_C];
    __shared__ float exv[CAP_C];
    __shared__ unsigned char sel2[CAP_C];
    const float* crow = cosm + (size_t)row * N;
    float v[16];
    unsigned fl = 0;
#pragma unroll
    for (int q = 0; q < 4; ++q) {
        float4 f4 = *(const float4*)&crow[tid * 16 + q * 4];
        v[q * 4 + 0] = f4.x; v[q * 4 + 1] = f4.y;
        v[q * 4 + 2] = f4.z; v[q * 4 + 3] = f4.w;
    }
#pragma unroll
    for (int c = 0; c < 16; ++c)
        if (v[c] > COS_THR) fl |= 1u << c;
    unsigned exm = 0;
#pragma unroll
    for (int t = 0; t < COS_K; ++t) {
        float best = -INFINITY; int bidx = 0x7fffffff;
#pragma unroll
        for (int c = 0; c < 16; ++c)
            if (!((exm >> c) & 1) && v[c] > best) { best = v[c]; bidx = tid * 16 + c; }
#pragma unroll
        for (int off = 32; off > 0; off >>= 1) {
            float v2 = __shfl_xor(best, off);
            int   i2 = __shfl_xor(bidx, off);
            if (v2 > best || (v2 == best && i2 < bidx)) { best = v2; bidx = i2; }
        }
        if ((bidx >> 4) == tid) exm |= 1u << (bidx & 15);
        if (lane == t) { wv[wid][t] = best; wi[wid][t] = bidx; }
    }
    __syncthreads();
    if (wid == 0) {
        float mv = -INFINITY; int mi = 0x7fffffff;
        if (lane < 40) { int g = lane / 10, s = lane - g * 10; mv = wv[g][s]; mi = wi[g][s]; }
        for (int t = 0; t < COS_K; ++t) {
            float best = mv; int bidx = mi;
#pragma unroll
            for (int off = 32; off > 0; off >>= 1) {
                float v2 = __shfl_xor(best, off);
                int   i2 = __shfl_xor(bidx, off);
                if (v2 > best || (v2 == best && i2 < bidx)) { best = v2; bidx = i2; }
            }
            if (mi == bidx) mv = -INFINITY;
            if (lane == 0) { win[t] = bidx; if (t == COS_K - 1) v10s = best; }
        }
    }
    __syncthreads();
    unsigned sel = 0;
#pragma unroll
    for (int t = 0; t < COS_K; ++t) {
        int wj = win[t];
        if ((wj >> 4) == tid) sel |= 1u << (wj & 15);
    }
    fl |= sel;
    float v10 = v10s;
    bool amb = false;
#pragma unroll
    for (int c = 0; c < 16; ++c) {
        if ((sel >> c) & 1) continue;
        float vc = v[c];
        if (vc > v10 - GAPWIN || fabsf(vc - COS_THR) < GAPWIN) amb = true;
    }
    unsigned long long ab = __ballot(amb);
    if (lane == 0) wamb[wid] = (ab != 0ull) ? 1 : 0;
    __syncthreads();
    bool blockamb = (wamb[0] | wamb[1] | wamb[2] | wamb[3]) != 0;
    if (blockamb) {
        unsigned cm = 0;
#pragma unroll
        for (int c = 0; c < 16; ++c)
            if (v[c] > v10 - GAPWIN || fabsf(v[c] - COS_THR) < GAPWIN) cm |= 1u << c;
        int ccnt2 = __popc(cm);
        int cscan = ccnt2;
#pragma unroll
        for (int off = 1; off < 64; off <<= 1) {
            int nv = __shfl_up(cscan, off);
            if (lane >= off) cscan += nv;
        }
        if (lane == 63) wtot[wid] = cscan;
        __syncthreads();
        int cbase = cscan - ccnt2;
        for (int w = 0; w < wid; ++w) cbase += wtot[w];
        {
            unsigned m = cm; int pos = cbase;
            while (m) {
                int c = __builtin_ctz(m); m &= m - 1;
                if (pos < CAP_C) cj[pos] = tid * 16 + c;
                ++pos;
            }
        }
        __syncthreads();
        int Mtot = wtot[0] + wtot[1] + wtot[2] + wtot[3];
        int M = Mtot < CAP_C ? Mtot : CAP_C;
        if (tid < M) {
            int j = cj[tid];
            float invr = norminv[row], invj = norminv[j];
            const float* xr = x + (size_t)row * IN_FT;
            const float* xj = x + (size_t)j * IN_FT;
            float acc = 0.f;
            for (int k = 0; k < IN_FT; ++k)
                acc = fmaf(xr[k] * invr, xj[k] * invj, acc);
            exv[tid] = acc;
        }
        __syncthreads();
        if (tid < M) {
            float vv = exv[tid]; int j = cj[tid];
            int rank = 0;
            for (int m2 = 0; m2 < M; ++m2) {
                float v2 = exv[m2]; int j2 = cj[m2];
                if (v2 > vv || (v2 == vv && j2 < j)) ++rank;
            }
            sel2[tid] = (rank < COS_K) ? 1 : 0;
        }
        __syncthreads();
        unsigned newfl = 0;
        {
            unsigned m = cm; int pos = cbase;
            unsigned done = 0;
            while (m) {
                int c = __builtin_ctz(m); m &= m - 1;
                bool f;
                if (pos < CAP_C) f = (exv[pos] > COS_THR) || sel2[pos];
                else             f = (v[c] > COS_THR);
                if (f) newfl |= 1u << c;
                done |= 1u << c;
                ++pos;
            }
#pragma unroll
            for (int c = 0; c < 16; ++c)
                if (!((done >> c) & 1) && v[c] > COS_THR) newfl |= 1u << c;
        }
        fl = newfl;
        __syncthreads();
    }
    unsigned flp = __shfl_xor(fl, 1);
    if (!(tid & 1))
        maskT[(size_t)(tid >> 1) * N + row] = (fl & 0xffffu) | (flp << 16);
    int cnt = __popc(fl);
    int scan = cnt;
#pragma unroll
    for (int off = 1; off < 64; off <<= 1) {
        int nv = __shfl_up(scan, off);
        if (lane >= off) scan += nv;
    }
    if (lane == 63) wtot[wid] = scan;
    __syncthreads();
    int base = scan - cnt;
    for (int w = 0; w < wid; ++w) base += wtot[w];
    unsigned m = fl;
    int pos = base;
    while (m) {
        int c = __builtin_ctz(m); m &= m - 1;
        int j = tid * 16 + c;
        if (pos < CAP) {
            size_t ofs = (size_t)row * N + j;
            rlist[(size_t)row * CAP + pos] = j;
            rval[(size_t)row * CAP + pos] = w2[ofs] * Hmat[ofs];
        }
        ++pos;
    }
    if (tid == 0) {
        int tot = wtot[0] + wtot[1] + wtot[2] + wtot[3];
        rcnt[row] = tot < CAP ? tot : CAP;
    }
}

// ---------- split proj_w into bf16 (hi, lo) ----------
__global__ __launch_bounds__(256) void cast_w_k(const float* __restrict__ w,
                                                unsigned short* __restrict__ wh,
                                                unsigned short* __restrict__ wl) {
    int i4 = blockIdx.x * 256 + threadIdx.x;   // 65536 float4s
    float4 f = ((const float4*)w)[i4];
    ushort4 hi, lo;
    hi.x = f2bf(f.x); lo.x = f2bf(f.x - bf2f(hi.x));
    hi.y = f2bf(f.y); lo.y = f2bf(f.y - bf2f(hi.y));
    hi.z = f2bf(f.z); lo.z = f2bf(f.z - bf2f(hi.z));
    hi.w = f2bf(f.w); lo.w = f2bf(f.w - bf2f(hi.w));
    ((ushort4*)wh)[i4] = hi;
    ((ushort4*)wl)[i4] = lo;
}

// ---------- h = nrm * (xn @ proj_w^T) + b via bf16x3 MFMA ----------
__global__ __launch_bounds__(256) void proj_mfma_k(const unsigned short* __restrict__ xh,
                                                   const unsigned short* __restrict__ xl,
                                                   const unsigned short* __restrict__ wh,
                                                   const unsigned short* __restrict__ wl,
                                                   const float* __restrict__ bias,
                                                   const float* __restrict__ nrm,
                                                   float* __restrict__ h) {
    int tid = threadIdx.x;
    int wave = tid >> 6, l = tid & 63;
    int m0 = blockIdx.y * 64 + wave * 16;
    int n0 = blockIdx.x * 64;
    int lr = l & 15;
    int kq = (l >> 4) * 8;
    const unsigned short* pah = xh + (size_t)(m0 + lr) * IN_FT + kq;
    const unsigned short* pal = xl + (size_t)(m0 + lr) * IN_FT + kq;
    f32x4 acc[4] = {};
    for (int k0 = 0; k0 < IN_FT; k0 += 32) {
        s16x8 ah = *(const s16x8*)(pah + k0);
        s16x8 al = *(const s16x8*)(pal + k0);
#pragma unroll
        for (int g = 0; g < 4; ++g) {
            const unsigned short* pbh = wh + (size_t)(n0 + g * 16 + lr) * IN_FT + kq + k0;
            const unsigned short* pbl = wl + (size_t)(n0 + g * 16 + lr) * IN_FT + kq + k0;
            s16x8 bh = *(const s16x8*)pbh;
            s16x8 bl = *(const s16x8*)pbl;
            acc[g] = __builtin_amdgcn_mfma_f32_16x16x32_bf16(ah, bh, acc[g], 0, 0, 0);
            acc[g] = __builtin_amdgcn_mfma_f32_16x16x32_bf16(ah, bl, acc[g], 0, 0, 0);
            acc[g] = __builtin_amdgcn_mfma_f32_16x16x32_bf16(al, bh, acc[g], 0, 0, 0);
        }
    }
#pragma unroll
    for (int g = 0; g < 4; ++g)
#pragma unroll
        for (int r = 0; r < 4; ++r) {
            int m = m0 + (l >> 4) * 4 + r;
            int n = n0 + g * 16 + lr;
            h[(size_t)m * OUT_FT + n] = nrm[m] * acc[g][r] + bias[n];
        }
}

// ---------- column build pass 1: per-(v-chunk, e) bit counts ----------
__global__ __launch_bounds__(256) void count_cols_k(const unsigned* __restrict__ maskT,
                                                    int* __restrict__ cnt16) {
    __shared__ unsigned ch[8][256];
    int tid = threadIdx.x;
    int eb = blockIdx.x, chunk = blockIdx.y;
    int wbase = eb * 8, v0 = chunk * 256;
#pragma unroll
    for (int i = 0; i < 8; ++i)
        ch[i][tid] = maskT[(size_t)(wbase + i) * N + v0 + tid];
    __syncthreads();
    int wl = tid >> 5, bp = tid & 31;
    int cnt = 0;
#pragma unroll 8
    for (int v = 0; v < 256; ++v) cnt += (ch[wl][v] >> bp) & 1;
    cnt16[chunk * N + eb * 256 + tid] = cnt;
}

// ---------- column build pass 2: fill at prefix offsets (deterministic) ----------
__global__ __launch_bounds__(256) void fill_cols_k(const unsigned* __restrict__ maskT,
                                                   const int* __restrict__ cnt16,
                                                   const float* __restrict__ w1,
                                                   const float* __restrict__ Hmat,
                                                   int* __restrict__ elist,
                                                   float* __restrict__ eval_,
                                                   int* __restrict__ ecnt) {
    __shared__ unsigned ch[8][256];
    int tid = threadIdx.x;
    int eb = blockIdx.x, chunk = blockIdx.y;
    int e = eb * 256 + tid;
    int wbase = eb * 8, v0 = chunk * 256;
#pragma unroll
    for (int i = 0; i < 8; ++i)
        ch[i][tid] = maskT[(size_t)(wbase + i) * N + v0 + tid];
    int pos = 0;
    for (int c = 0; c < chunk; ++c) pos += cnt16[c * N + e];
    __syncthreads();
    int wl = tid >> 5;
    unsigned bit = 1u << (tid & 31);
    for (int v = 0; v < 256; ++v) {
        if (ch[wl][v] & bit) {
            if (pos < CAP) {
                size_t ofs = (size_t)(v0 + v) * N + e;
                elist[(size_t)e * CAP + pos] = v0 + v;
                eval_[(size_t)e * CAP + pos] = w1[ofs] * Hmat[ofs];
            }
            ++pos;
        }
    }
    if (chunk == 15) ecnt[e] = pos < CAP ? pos : CAP;
}

// ---------- dst[i,:] = (1/max(sum|val|,eps)) * sum val*src[list,:] ----------
__global__ __launch_bounds__(256) void spmm_k(const int* __restrict__ list,
                                              const float* __restrict__ val,
                                              const int* __restrict__ cnt,
                                              const float* __restrict__ src,
                                              float* __restrict__ dst) {
    int i = blockIdx.x;
    int f2 = threadIdx.x;
    int c = cnt[i];
    float ssum = 0.f;
    for (int t = 0; t < c; ++t) ssum += fabsf(val[(size_t)i * CAP + t]);
    float acc0 = 0.f, acc1 = 0.f;
    for (int t = 0; t < c; ++t) {
        int j = list[(size_t)i * CAP + t];
        float a = val[(size_t)i * CAP + t];
        float2 s = *(const float2*)&src[(size_t)j * OUT_FT + f2 * 2];
        acc0 += a * s.x;
        acc1 += a * s.y;
    }
    float sc = 1.0f / fmaxf(ssum, EPSN);
    float2 o = make_float2(acc0 * sc, acc1 * sc);
    *(float2*)&dst[(size_t)i * OUT_FT + f2 * 2] = o;
}

extern "C" void kernel_launch(void* const* d_in, const int* in_sizes, int n_in,
                              void* d_out, int out_size, void* d_ws, size_t ws_size,
                              hipStream_t stream) {
    const float* x      = (const float*)d_in[0];   // [4096,512]
    const float* Hmat   = (const float*)d_in[1];   // [4096,4096]
    const float* proj_w = (const float*)d_in[2];   // [512,512]
    const float* proj_b = (const float*)d_in[3];   // [512]
    const float* w1     = (const float*)d_in[4];   // [4096,4096]
    const float* w2     = (const float*)d_in[5];   // [4096,4096]
    float* out = (float*)d_out;

    char* ws = (char*)d_ws;
    unsigned short* xnh   = (unsigned short*)(ws + 0);         // 4 MB
    unsigned short* xnl   = (unsigned short*)(ws + 4194304);   // 4 MB
    float*          cosm  = (float*)(ws + 8388608);            // 64 MB, dead after topk_fb
    int*            elist = (int*)  (ws + 8388608);            // 4 MB (aliases dead cos)
    float*          eval_ = (float*)(ws + 12582912);           // 4 MB (aliases dead cos)
    float*          h     = (float*)(ws + 25165824);           // 8 MB (aliases dead cos)
    float*          h2    = (float*)(ws + 33554432);           // 8 MB (aliases dead cos)
    unsigned short* whi   = (unsigned short*)(ws + 50331648);  // 512 KB (aliases dead cos)
    unsigned short* wlo   = (unsigned short*)(ws + 50855936);  // 512 KB (aliases dead cos)
    int*            cnt16 = (int*)(ws + 52428800);             // 256 KB (aliases dead cos)
    unsigned*       maskT = (unsigned*)(ws + 75497472);        // 2 MB
    int*            ecnt    = (int*)(ws + 77594624);           // 16 KB
    int*            rcnt    = (int*)(ws + 77611008);           // 16 KB
    float*          norminv = (float*)(ws + 77627392);         // 16 KB
    float*          nrm     = (float*)(ws + 77643776);         // 16 KB
    int*            fbflag  = (int*)(ws + 77660160);           // 16 KB
    int*            ccnt    = (int*)(ws + 77676544);           // 16 KB
    int*            rlist   = (int*)(ws + 77692928);           // 4 MB
    float*          rval    = (float*)(ws + 81887232);         // 4 MB
    float*          cval    = (float*)(ws + 86081536);         // 3 MB  [4096][192]
    int*            cidx    = (int*)(ws + 89227264);           // 3 MB  -> ends 92.4 MB

    // 1. norms + bf16 hi/lo of xn; zero candidate counters + fallback flags
    rownorm_k<<<N, 256, 0, stream>>>(x, xnh, xnl, norminv, nrm, ccnt, fbflag);
    // 2. approx cos: upper-tri MFMA + mirror + candidate emission (+dense C)
    cos_gemm_k<<<CNB * (CNB + 1) / 2, 256, 0, stream>>>(xnh, xnl, cosm, ccnt, cval, cidx);
    // 3. fast top-k over candidate lists (sets fbflag on any assumption break)
    topk_fast_k<<<N, 256, 0, stream>>>(cval, cidx, ccnt, x, norminv, maskT,
                                       w2, Hmat, rlist, rval, rcnt, fbflag);
    // 4. fallback rows: r15 full path from dense cos (before cos dies)
    topk_fb_k<<<N, 256, 0, stream>>>(fbflag, cosm, x, norminv, maskT,
                                     w2, Hmat, rlist, rval, rcnt);
    // 5. h = nrm*(xn @ proj_w^T) + b (cos region now dead; h aliases it)
    cast_w_k<<<256, 256, 0, stream>>>(proj_w, whi, wlo);
    proj_mfma_k<<<dim3(OUT_FT / 64, N / 64), 256, 0, stream>>>(xnh, xnl, whi, wlo,
                                                               proj_b, nrm, h);
    // 6. column lists: count -> fill at prefix offsets
    count_cols_k<<<dim3(16, 16), 256, 0, stream>>>(maskT, cnt16);
    fill_cols_k<<<dim3(16, 16), 256, 0, stream>>>(maskT, cnt16, w1, Hmat, elist, eval_, ecnt);
    // 7. h2[e,:] = normalize . gather-sum over column lists
    spmm_k<<<N, 256, 0, stream>>>(elist, eval_, ecnt, h, h2);
    // 8. out[v,:] = normalize . gather-sum over row lists
    spmm_k<<<N, 256, 0, stream>>>(rlist, rval, rcnt, h2, out);
}

// Round 18
// 260.310 us; speedup vs baseline: 1.5719x; 1.5719x over previous
//
#include <hip/hip_runtime.h>
#include <hip/hip_bf16.h>
#include <math.h>

#define N 4096
#define IN_FT 512
#define OUT_FT 512
#define COS_THR 0.5f
#define COS_K 10
#define EPSN 1e-12f
#define CAP 256          // max stored nnz per row/col (actual ~10)
#define NW (N / 32)      // bitmask words per row
#define CAP_C 128        // candidate slots per flagged row (fix path)
#define GAPWIN 2e-4f     // ambiguity window; bf16x3 error ~1.5e-5 + mirror ulp
#define CNB 32           // 128-blocks per side
#define T0 0.08f         // candidate threshold (data-checked, fallback-safe)
#define CAPT 256         // per-row candidate capacity (mean ~144)

typedef short s16x8 __attribute__((ext_vector_type(8)));
typedef float f32x4 __attribute__((ext_vector_type(4)));

__device__ __forceinline__ unsigned short f2bf(float f) {
    unsigned u = __float_as_uint(f);
    u += 0x7fff + ((u >> 16) & 1);          // RNE to bf16
    return (unsigned short)(u >> 16);
}
__device__ __forceinline__ float bf2f(unsigned short h) {
    return __uint_as_float(((unsigned)h) << 16);
}
__device__ __forceinline__ void gload_lds16(const void* g, void* l) {
    __builtin_amdgcn_global_load_lds(
        (const __attribute__((address_space(1))) void*)g,
        (__attribute__((address_space(3))) void*)l, 16, 0, 0);
}

// ---------- row-normalize: bf16 hi/lo of xn + norms; zero fbflag ----------
__global__ __launch_bounds__(256) void rownorm_k(const float* __restrict__ x,
                                                 unsigned short* __restrict__ xnh,
                                                 unsigned short* __restrict__ xnl,
                                                 float* __restrict__ norminv,
                                                 float* __restrict__ nrm,
                                                 int* __restrict__ fbflag) {
    int row = blockIdx.x;
    const float* xr = x + (size_t)row * IN_FT;
    float s = 0.f;
    for (int j = threadIdx.x; j < IN_FT; j += 256) { float v = xr[j]; s += v * v; }
    __shared__ float red[256];
    red[threadIdx.x] = s; __syncthreads();
    for (int off = 128; off > 0; off >>= 1) {
        if (threadIdx.x < off) red[threadIdx.x] += red[threadIdx.x + off];
        __syncthreads();
    }
    float nr = fmaxf(sqrtf(red[0]), 1e-12f);
    float inv = 1.0f / nr;
    if (threadIdx.x == 0) { norminv[row] = inv; nrm[row] = nr; fbflag[row] = 0; }
    for (int j = threadIdx.x; j < IN_FT; j += 256) {
        float v = xr[j] * inv;                 // same op the fix path replays
        unsigned short hi = f2bf(v);
        unsigned short lo = f2bf(v - bf2f(hi));
        xnh[(size_t)row * IN_FT + j] = hi;
        xnl[(size_t)row * IN_FT + j] = lo;
    }
}

// ---------- approx cos: bf16x3 MFMA, upper-tri + mirror + BITMASK emission ----------
// Candidate emission is contention-free: each (row, col-block) pair is owned
// by exactly one block (upper or mirror), so per-row >T0 bitmasks are built in
// LDS (atomicOr, ~3.5% density) and stored with exclusive coalesced writes.
// No global atomics (r17's ccnt atomicAdd storm was a 3x regression).
__global__ __launch_bounds__(256) void cos_gemm_k(const unsigned short* __restrict__ xh,
                                                  const unsigned short* __restrict__ xl,
                                                  float* __restrict__ C,
                                                  unsigned* __restrict__ cbits) {
    __shared__ __align__(16) unsigned short As[2][128 * 32];
    __shared__ __align__(16) unsigned short Bs[2][128 * 32];
    __shared__ unsigned mbU[128][4];
    __shared__ unsigned mbM[128][4];
    int bid = blockIdx.x;                      // 0 .. 527
    int t = (bid & 7) * 66 + (bid >> 3);       // XCD-chunked bijection
    int by = 0;
    while (t >= CNB - by) { t -= CNB - by; ++by; }
    int bx = by + t;                           // by <= bx
    int tid = threadIdx.x;
    int wave = tid >> 6, l = tid & 63;
    int bi = by * 128, bj = bx * 128;
    int wm = wave >> 1, wn = wave & 1;
    int lm0 = wm * 64, ln0 = wn * 64;
    int lr4 = l >> 2;
    int lc4s = (((l & 3) ^ ((l >> 3) & 3)) * 8);   // swizzled SOURCE chunk
    int lr = l & 15, lg = l >> 4;
    int kqs = (((l >> 4) ^ ((l >> 1) & 3)) * 8);   // swizzled read chunk
    f32x4 acc[4][4] = {};
    int buf = 0;
#pragma unroll
    for (int q = 0; q < 2; ++q) {
        int r0 = (wave + q * 4) * 16;
        gload_lds16(xh + (size_t)(bi + r0 + lr4) * IN_FT + lc4s, &As[0][r0 * 32]);
        gload_lds16(xh + (size_t)(bj + r0 + lr4) * IN_FT + lc4s, &Bs[0][r0 * 32]);
    }
    asm volatile("s_waitcnt vmcnt(0)" ::: "memory");
    __syncthreads();
    for (int kt = 0; kt < 48; ++kt) {
        if (kt + 1 < 48) {
            int p = (kt + 1) >> 4;
            int kc = ((kt + 1) & 15) * 32;
            const unsigned short* sa = (p == 2) ? xl : xh;
            const unsigned short* sb = (p == 1) ? xl : xh;
#pragma unroll
            for (int q = 0; q < 2; ++q) {
                int r0 = (wave + q * 4) * 16;
                gload_lds16(sa + (size_t)(bi + r0 + lr4) * IN_FT + kc + lc4s,
                            &As[buf ^ 1][r0 * 32]);
                gload_lds16(sb + (size_t)(bj + r0 + lr4) * IN_FT + kc + lc4s,
                            &Bs[buf ^ 1][r0 * 32]);
            }
        }
        s16x8 a[4], b[4];
#pragma unroll
        for (int mi = 0; mi < 4; ++mi)
            a[mi] = *(const s16x8*)&As[buf][(lm0 + mi * 16 + lr) * 32 + kqs];
#pragma unroll
        for (int ni = 0; ni < 4; ++ni)
            b[ni] = *(const s16x8*)&Bs[buf][(ln0 + ni * 16 + lr) * 32 + kqs];
#pragma unroll
        for (int mi = 0; mi < 4; ++mi)
#pragma unroll
            for (int ni = 0; ni < 4; ++ni)
                acc[mi][ni] = __builtin_amdgcn_mfma_f32_16x16x32_bf16(a[mi], b[ni], acc[mi][ni], 0, 0, 0);
        asm volatile("s_waitcnt vmcnt(0)" ::: "memory");
        __syncthreads();
        buf ^= 1;
    }
    // zero LDS bitmasks
    ((unsigned*)mbU)[tid] = 0; ((unsigned*)mbU)[tid + 256] = 0;
    ((unsigned*)mbM)[tid] = 0; ((unsigned*)mbM)[tid + 256] = 0;
    __syncthreads();
    // upper block store + bitmask
#pragma unroll
    for (int mi = 0; mi < 4; ++mi)
#pragma unroll
        for (int r = 0; r < 4; ++r) {
            int m = bi + lm0 + mi * 16 + lg * 4 + r;
#pragma unroll
            for (int ni = 0; ni < 4; ++ni) {
                float val = acc[mi][ni][r];
                int n = bj + ln0 + ni * 16 + lr;
                C[(size_t)m * N + n] = val;
                if (val > T0)
                    atomicOr(&mbU[m - bi][(n - bj) >> 5], 1u << (n & 31));
            }
        }
    // mirrored store + bitmask (values bit-identical: IEEE a*b==b*a)
    if (bx != by) {
#pragma unroll
        for (int ni = 0; ni < 4; ++ni) {
            int cc = bj + ln0 + ni * 16 + lr;
#pragma unroll
            for (int mi = 0; mi < 4; ++mi) {
                float4 s = make_float4(acc[mi][ni][0], acc[mi][ni][1],
                                       acc[mi][ni][2], acc[mi][ni][3]);
                *(float4*)&C[(size_t)cc * N + bi + lm0 + mi * 16 + lg * 4] = s;
#pragma unroll
                for (int r = 0; r < 4; ++r) {
                    float val = acc[mi][ni][r];
                    if (val > T0) {
                        int col = bi + lm0 + mi * 16 + lg * 4 + r;
                        atomicOr(&mbM[cc - bj][(col - bi) >> 5], 1u << (col & 31));
                    }
                }
            }
        }
    }
    __syncthreads();
    // exclusive coalesced writeout (each (row, col-block) owned by one block)
#pragma unroll
    for (int q = 0; q < 2; ++q) {
        int idx = tid + q * 256;               // 0..511
        int r = idx >> 2, w = idx & 3;
        cbits[(size_t)(bi + r) * NW + bx * 4 + w] = mbU[r][w];
        if (bx != by)
            cbits[(size_t)(bj + r) * NW + by * 4 + w] = mbM[r][w];
    }
}

// ---------- fast top-k from candidate bitmask + gathered values ----------
// Candidate set = {v > T0} (deterministic). Selection/window/fix use the
// (value desc, index asc) total order -> order-invariant, equals r15/r16
// validated results. Guards (uniform): Mc in [10,CAPT], v10-GAPWIN > T0,
// Mw <= CAP_C; else fbflag -> fallback from dense cosm.
__global__ __launch_bounds__(256) void topk_fast_k(const unsigned* __restrict__ cbits,
                                                   const float* __restrict__ cosm,
                                                   const float* __restrict__ x,
                                                   const float* __restrict__ norminv,
                                                   unsigned* __restrict__ maskT,
                                                   const float* __restrict__ w2,
                                                   const float* __restrict__ Hmat,
                                                   int* __restrict__ rlist,
                                                   float* __restrict__ rval,
                                                   int* __restrict__ rcnt,
                                                   int* __restrict__ fbflag) {
    int row = blockIdx.x, tid = threadIdx.x;
    int lane = tid & 63, wid = tid >> 6;
    __shared__ int   win[10];
    __shared__ float v10s;
    __shared__ int   wred[4];
    __shared__ float cv2[CAPT];
    __shared__ int   ci2[CAPT];
    __shared__ int   cjp[CAP_C];
    __shared__ int   cjj[CAP_C];
    __shared__ float exv[CAP_C];
    __shared__ unsigned char selw[CAP_C];
    __shared__ unsigned char candflag[CAPT];
    __shared__ unsigned ldsmask[NW];
    // --- read bitmask, count, compact candidates (ascending j) ---
    unsigned word = 0; int cnt = 0;
    if (tid < NW) { word = cbits[(size_t)row * NW + tid]; cnt = __popc(word); }
    int scan = cnt;
#pragma unroll
    for (int off = 1; off < 64; off <<= 1) {
        int nv = __shfl_up(scan, off);
        if (lane >= off) scan += nv;
    }
    if (lane == 63) wred[wid] = scan;
    __syncthreads();
    int Mc = wred[0] + wred[1];                // waves 2,3 hold no words
    if (Mc < COS_K || Mc > CAPT) { if (tid == 0) fbflag[row] = 1; return; }
    if (tid < NW) {
        int base = scan - cnt + (wid == 1 ? wred[0] : 0);
        unsigned m = word; int pos = base;
        while (m) {
            int b = __builtin_ctz(m); m &= m - 1;
            int j = tid * 32 + b;
            ci2[pos] = j;
            cv2[pos] = cosm[(size_t)row * N + j];   // scattered, L3-resident
            ++pos;
        }
    }
    __syncthreads();
    // --- wave 0: top-10 over candidates, (value desc, index asc) order ---
    if (wid == 0) {
        float cv[4]; int ci[4];
#pragma unroll
        for (int s = 0; s < 4; ++s) {
            int p = s * 64 + lane;
            bool ok = p < Mc;
            cv[s] = ok ? cv2[p] : -INFINITY;
            ci[s] = ok ? ci2[p] : 0x7fffffff;
        }
        unsigned exm = 0;
        for (int t = 0; t < COS_K; ++t) {
            float best = -INFINITY; int bidx = 0x7fffffff;
#pragma unroll
            for (int s = 0; s < 4; ++s)
                if (!((exm >> s) & 1) &&
                    (cv[s] > best || (cv[s] == best && ci[s] < bidx))) { best = cv[s]; bidx = ci[s]; }
#pragma unroll
            for (int off = 32; off > 0; off >>= 1) {
                float v2 = __shfl_xor(best, off);
                int   i2 = __shfl_xor(bidx, off);
                if (v2 > best || (v2 == best && i2 < bidx)) { best = v2; bidx = i2; }
            }
#pragma unroll
            for (int s = 0; s < 4; ++s)        // indices unique -> owner marks
                if (ci[s] == bidx) exm |= 1u << s;
            if (lane == 0) { win[t] = bidx; if (t == COS_K - 1) v10s = best; }
        }
    }
    __syncthreads();
    float v10 = v10s;
    if (v10 - GAPWIN <= T0) { if (tid == 0) fbflag[row] = 1; return; }  // uniform
    bool valid = tid < Mc;
    float myv = 0.f; int myj = -1;
    if (valid) { myv = cv2[tid]; myj = ci2[tid]; }
    bool isw = valid && ((myv > v10 - GAPWIN) || (fabsf(myv - COS_THR) < GAPWIN));
    unsigned long long wb = __ballot(isw);
    __syncthreads();                            // wred free for rewrite
    if (lane == 0) wred[wid] = __popcll(wb);
    __syncthreads();
    int Mw = wred[0] + wred[1] + wred[2] + wred[3];
    if (Mw > CAP_C) { if (tid == 0) fbflag[row] = 1; return; }          // uniform
    bool inwin = false;
    if (valid) {
#pragma unroll
        for (int t = 0; t < COS_K; ++t) if (win[t] == myj) inwin = true;
        candflag[tid] = ((myv > COS_THR) || inwin) ? 1 : 0;
    }
    if (Mw > COS_K) {                           // ambiguity -> inline exact fix
        int pb = isw ? 1 : 0;
        int scw = pb;
#pragma unroll
        for (int off = 1; off < 64; off <<= 1) {
            int nv = __shfl_up(scw, off);
            if (lane >= off) scw += nv;
        }
        int base = scw - pb;
        for (int w = 0; w < wid; ++w) base += wred[w];
        if (pb) cjp[base] = tid;
        __syncthreads();
        if (tid < Mw) {        // exact dots: identical serial ascending-k chain
            int j = ci2[cjp[tid]];
            cjj[tid] = j;
            float invr = norminv[row], invj = norminv[j];
            const float* xr = x + (size_t)row * IN_FT;
            const float* xj = x + (size_t)j * IN_FT;
            float acc = 0.f;
            for (int k = 0; k < IN_FT; ++k)
                acc = fmaf(xr[k] * invr, xj[k] * invj, acc);
            exv[tid] = acc;
        }
        __syncthreads();
        if (tid < Mw) {        // rank with identical comparator
            float vv = exv[tid]; int j = cjj[tid];
            int rank = 0;
            for (int m2 = 0; m2 < Mw; ++m2) {
                float v2 = exv[m2]; int j2 = cjj[m2];
                if (v2 > vv || (v2 == vv && j2 < j)) ++rank;
            }
            selw[tid] = (rank < COS_K) ? 1 : 0;
        }
        __syncthreads();
        if (tid < Mw)
            candflag[cjp[tid]] = ((exv[tid] > COS_THR) || selw[tid]) ? 1 : 0;
    }
    __syncthreads();
    // --- build final bitmask from flagged candidates ---
    if (tid < NW) ldsmask[tid] = 0;
    __syncthreads();
    if (valid && candflag[tid]) atomicOr(&ldsmask[myj >> 5], 1u << (myj & 31));
    __syncthreads();
    if (tid < NW) maskT[(size_t)tid * N + row] = ldsmask[tid];
    // --- row list (ascending j) ---
    unsigned fw = 0; int fc = 0;
    if (tid < NW) { fw = ldsmask[tid]; fc = __popc(fw); }
    int scan2 = fc;
#pragma unroll
    for (int off = 1; off < 64; off <<= 1) {
        int nv = __shfl_up(scan2, off);
        if (lane >= off) scan2 += nv;
    }
    __syncthreads();                            // wred free for rewrite
    if (lane == 63) wred[wid] = scan2;
    __syncthreads();
    if (tid < NW) {
        int base2 = scan2 - fc + (wid == 1 ? wred[0] : 0);
        unsigned m = fw; int pos = base2;
        while (m) {
            int b = __builtin_ctz(m); m &= m - 1;
            int j = tid * 32 + b;
            if (pos < CAP) {
                size_t ofs = (size_t)row * N + j;
                rlist[(size_t)row * CAP + pos] = j;
                rval[(size_t)row * CAP + pos] = w2[ofs] * Hmat[ofs];
            }
            ++pos;
        }
    }
    if (tid == 0) {
        int tot = wred[0] + wred[1];
        rcnt[row] = tot < CAP ? tot : CAP;
    }
}

// ---------- fallback: r15 full path from dense cos (guarded, ~never runs) ----------
__global__ __launch_bounds__(256) void topk_fb_k(const int* __restrict__ fbflag,
                                                 const float* __restrict__ cosm,
                                                 const float* __restrict__ x,
                                                 const float* __restrict__ norminv,
                                                 unsigned* __restrict__ maskT,
                                                 const float* __restrict__ w2,
                                                 const float* __restrict__ Hmat,
                                                 int* __restrict__ rlist,
                                                 float* __restrict__ rval,
                                                 int* __restrict__ rcnt) {
    int row = blockIdx.x;
    if (!fbflag[row]) return;
    int tid = threadIdx.x;
    int lane = tid & 63, wid = tid >> 6;
    __shared__ float wv[4][10];
    __shared__ int   wi[4][10];
    __shared__ int   win[10];
    __shared__ float v10s;
    __shared__ int   wtot[4];
    __shared__ int   wamb[4];
    __shared__ int   cj[CAP_C];
    __shared__ float exv[CAP_C];
    __shared__ unsigned char sel2[CAP_C];
    const float* crow = cosm + (size_t)row * N;
    float v[16];
    unsigned fl = 0;
#pragma unroll
    for (int q = 0; q < 4; ++q) {
        float4 f4 = *(const float4*)&crow[tid * 16 + q * 4];
        v[q * 4 + 0] = f4.x; v[q * 4 + 1] = f4.y;
        v[q * 4 + 2] = f4.z; v[q * 4 + 3] = f4.w;
    }
#pragma unroll
    for (int c = 0; c < 16; ++c)
        if (v[c] > COS_THR) fl |= 1u << c;
    unsigned exm = 0;
#pragma unroll
    for (int t = 0; t < COS_K; ++t) {
        float best = -INFINITY; int bidx = 0x7fffffff;
#pragma unroll
        for (int c = 0; c < 16; ++c)
            if (!((exm >> c) & 1) && v[c] > best) { best = v[c]; bidx = tid * 16 + c; }
#pragma unroll
        for (int off = 32; off > 0; off >>= 1) {
            float v2 = __shfl_xor(best, off);
            int   i2 = __shfl_xor(bidx, off);
            if (v2 > best || (v2 == best && i2 < bidx)) { best = v2; bidx = i2; }
        }
        if ((bidx >> 4) == tid) exm |= 1u << (bidx & 15);
        if (lane == t) { wv[wid][t] = best; wi[wid][t] = bidx; }
    }
    __syncthreads();
    if (wid == 0) {
        float mv = -INFINITY; int mi = 0x7fffffff;
        if (lane < 40) { int g = lane / 10, s = lane - g * 10; mv = wv[g][s]; mi = wi[g][s]; }
        for (int t = 0; t < COS_K; ++t) {
            float best = mv; int bidx = mi;
#pragma unroll
            for (int off = 32; off > 0; off >>= 1) {
                float v2 = __shfl_xor(best, off);
                int   i2 = __shfl_xor(bidx, off);
                if (v2 > best || (v2 == best && i2 < bidx)) { best = v2; bidx = i2; }
            }
            if (mi == bidx) mv = -INFINITY;
            if (lane == 0) { win[t] = bidx; if (t == COS_K - 1) v10s = best; }
        }
    }
    __syncthreads();
    unsigned sel = 0;
#pragma unroll
    for (int t = 0; t < COS_K; ++t) {
        int wj = win[t];
        if ((wj >> 4) == tid) sel |= 1u << (wj & 15);
    }
    fl |= sel;
    float v10 = v10s;
    bool amb = false;
#pragma unroll
    for (int c = 0; c < 16; ++c) {
        if ((sel >> c) & 1) continue;
        float vc = v[c];
        if (vc > v10 - GAPWIN || fabsf(vc - COS_THR) < GAPWIN) amb = true;
    }
    unsigned long long ab = __ballot(amb);
    if (lane == 0) wamb[wid] = (ab != 0ull) ? 1 : 0;
    __syncthreads();
    bool blockamb = (wamb[0] | wamb[1] | wamb[2] | wamb[3]) != 0;
    if (blockamb) {
        unsigned cm = 0;
#pragma unroll
        for (int c = 0; c < 16; ++c)
            if (v[c] > v10 - GAPWIN || fabsf(v[c] - COS_THR) < GAPWIN) cm |= 1u << c;
        int ccnt2 = __popc(cm);
        int cscan = ccnt2;
#pragma unroll
        for (int off = 1; off < 64; off <<= 1) {
            int nv = __shfl_up(cscan, off);
            if (lane >= off) cscan += nv;
        }
        if (lane == 63) wtot[wid] = cscan;
        __syncthreads();
        int cbase = cscan - ccnt2;
        for (int w = 0; w < wid; ++w) cbase += wtot[w];
        {
            unsigned m = cm; int pos = cbase;
            while (m) {
                int c = __builtin_ctz(m); m &= m - 1;
                if (pos < CAP_C) cj[pos] = tid * 16 + c;
                ++pos;
            }
        }
        __syncthreads();
        int Mtot = wtot[0] + wtot[1] + wtot[2] + wtot[3];
        int M = Mtot < CAP_C ? Mtot : CAP_C;
        if (tid < M) {
            int j = cj[tid];
            float invr = norminv[row], invj = norminv[j];
            const float* xr = x + (size_t)row * IN_FT;
            const float* xj = x + (size_t)j * IN_FT;
            float acc = 0.f;
            for (int k = 0; k < IN_FT; ++k)
                acc = fmaf(xr[k] * invr, xj[k] * invj, acc);
            exv[tid] = acc;
        }
        __syncthreads();
        if (tid < M) {
            float vv = exv[tid]; int j = cj[tid];
            int rank = 0;
            for (int m2 = 0; m2 < M; ++m2) {
                float v2 = exv[m2]; int j2 = cj[m2];
                if (v2 > vv || (v2 == vv && j2 < j)) ++rank;
            }
            sel2[tid] = (rank < COS_K) ? 1 : 0;
        }
        __syncthreads();
        unsigned newfl = 0;
        {
            unsigned m = cm; int pos = cbase;
            unsigned done = 0;
            while (m) {
                int c = __builtin_ctz(m); m &= m - 1;
                bool f;
                if (pos < CAP_C) f = (exv[pos] > COS_THR) || sel2[pos];
                else             f = (v[c] > COS_THR);
                if (f) newfl |= 1u << c;
                done |= 1u << c;
                ++pos;
            }
#pragma unroll
            for (int c = 0; c < 16; ++c)
                if (!((done >> c) & 1) && v[c] > COS_THR) newfl |= 1u << c;
        }
        fl = newfl;
        __syncthreads();
    }
    unsigned flp = __shfl_xor(fl, 1);
    if (!(tid & 1))
        maskT[(size_t)(tid >> 1) * N + row] = (fl & 0xffffu) | (flp << 16);
    int cnt = __popc(fl);
    int scan = cnt;
#pragma unroll
    for (int off = 1; off < 64; off <<= 1) {
        int nv = __shfl_up(scan, off);
        if (lane >= off) scan += nv;
    }
    if (lane == 63) wtot[wid] = scan;
    __syncthreads();
    int base = scan - cnt;
    for (int w = 0; w < wid; ++w) base += wtot[w];
    unsigned m = fl;
    int pos = base;
    while (m) {
        int c = __builtin_ctz(m); m &= m - 1;
        int j = tid * 16 + c;
        if (pos < CAP) {
            size_t ofs = (size_t)row * N + j;
            rlist[(size_t)row * CAP + pos] = j;
            rval[(size_t)row * CAP + pos] = w2[ofs] * Hmat[ofs];
        }
        ++pos;
    }
    if (tid == 0) {
        int tot = wtot[0] + wtot[1] + wtot[2] + wtot[3];
        rcnt[row] = tot < CAP ? tot : CAP;
    }
}

// ---------- split proj_w into bf16 (hi, lo) ----------
__global__ __launch_bounds__(256) void cast_w_k(const float* __restrict__ w,
                                                unsigned short* __restrict__ wh,
                                                unsigned short* __restrict__ wl) {
    int i4 = blockIdx.x * 256 + threadIdx.x;   // 65536 float4s
    float4 f = ((const float4*)w)[i4];
    ushort4 hi, lo;
    hi.x = f2bf(f.x); lo.x = f2bf(f.x - bf2f(hi.x));
    hi.y = f2bf(f.y); lo.y = f2bf(f.y - bf2f(hi.y));
    hi.z = f2bf(f.z); lo.z = f2bf(f.z - bf2f(hi.z));
    hi.w = f2bf(f.w); lo.w = f2bf(f.w - bf2f(hi.w));
    ((ushort4*)wh)[i4] = hi;
    ((ushort4*)wl)[i4] = lo;
}

// ---------- h = nrm * (xn @ proj_w^T) + b via bf16x3 MFMA ----------
__global__ __launch_bounds__(256) void proj_mfma_k(const unsigned short* __restrict__ xh,
                                                   const unsigned short* __restrict__ xl,
                                                   const unsigned short* __restrict__ wh,
                                                   const unsigned short* __restrict__ wl,
                                                   const float* __restrict__ bias,
                                                   const float* __restrict__ nrm,
                                                   float* __restrict__ h) {
    int tid = threadIdx.x;
    int wave = tid >> 6, l = tid & 63;
    int m0 = blockIdx.y * 64 + wave * 16;
    int n0 = blockIdx.x * 64;
    int lr = l & 15;
    int kq = (l >> 4) * 8;
    const unsigned short* pah = xh + (size_t)(m0 + lr) * IN_FT + kq;
    const unsigned short* pal = xl + (size_t)(m0 + lr) * IN_FT + kq;
    f32x4 acc[4] = {};
    for (int k0 = 0; k0 < IN_FT; k0 += 32) {
        s16x8 ah = *(const s16x8*)(pah + k0);
        s16x8 al = *(const s16x8*)(pal + k0);
#pragma unroll
        for (int g = 0; g < 4; ++g) {
            const unsigned short* pbh = wh + (size_t)(n0 + g * 16 + lr) * IN_FT + kq + k0;
            const unsigned short* pbl = wl + (size_t)(n0 + g * 16 + lr) * IN_FT + kq + k0;
            s16x8 bh = *(const s16x8*)pbh;
            s16x8 bl = *(const s16x8*)pbl;
            acc[g] = __builtin_amdgcn_mfma_f32_16x16x32_bf16(ah, bh, acc[g], 0, 0, 0);
            acc[g] = __builtin_amdgcn_mfma_f32_16x16x32_bf16(ah, bl, acc[g], 0, 0, 0);
            acc[g] = __builtin_amdgcn_mfma_f32_16x16x32_bf16(al, bh, acc[g], 0, 0, 0);
        }
    }
#pragma unroll
    for (int g = 0; g < 4; ++g)
#pragma unroll
        for (int r = 0; r < 4; ++r) {
            int m = m0 + (l >> 4) * 4 + r;
            int n = n0 + g * 16 + lr;
            h[(size_t)m * OUT_FT + n] = nrm[m] * acc[g][r] + bias[n];
        }
}

// ---------- column build pass 1: per-(v-chunk, e) bit counts ----------
__global__ __launch_bounds__(256) void count_cols_k(const unsigned* __restrict__ maskT,
                                                    int* __restrict__ cnt16) {
    __shared__ unsigned ch[8][256];
    int tid = threadIdx.x;
    int eb = blockIdx.x, chunk = blockIdx.y;
    int wbase = eb * 8, v0 = chunk * 256;
#pragma unroll
    for (int i = 0; i < 8; ++i)
        ch[i][tid] = maskT[(size_t)(wbase + i) * N + v0 + tid];
    __syncthreads();
    int wl = tid >> 5, bp = tid & 31;
    int cnt = 0;
#pragma unroll 8
    for (int v = 0; v < 256; ++v) cnt += (ch[wl][v] >> bp) & 1;
    cnt16[chunk * N + eb * 256 + tid] = cnt;
}

// ---------- column build pass 2: fill at prefix offsets (deterministic) ----------
__global__ __launch_bounds__(256) void fill_cols_k(const unsigned* __restrict__ maskT,
                                                   const int* __restrict__ cnt16,
                                                   const float* __restrict__ w1,
                                                   const float* __restrict__ Hmat,
                                                   int* __restrict__ elist,
                                                   float* __restrict__ eval_,
                                                   int* __restrict__ ecnt) {
    __shared__ unsigned ch[8][256];
    int tid = threadIdx.x;
    int eb = blockIdx.x, chunk = blockIdx.y;
    int e = eb * 256 + tid;
    int wbase = eb * 8, v0 = chunk * 256;
#pragma unroll
    for (int i = 0; i < 8; ++i)
        ch[i][tid] = maskT[(size_t)(wbase + i) * N + v0 + tid];
    int pos = 0;
    for (int c = 0; c < chunk; ++c) pos += cnt16[c * N + e];
    __syncthreads();
    int wl = tid >> 5;
    unsigned bit = 1u << (tid & 31);
    for (int v = 0; v < 256; ++v) {
        if (ch[wl][v] & bit) {
            if (pos < CAP) {
                size_t ofs = (size_t)(v0 + v) * N + e;
                elist[(size_t)e * CAP + pos] = v0 + v;
                eval_[(size_t)e * CAP + pos] = w1[ofs] * Hmat[ofs];
            }
            ++pos;
        }
    }
    if (chunk == 15) ecnt[e] = pos < CAP ? pos : CAP;
}

// ---------- dst[i,:] = (1/max(sum|val|,eps)) * sum val*src[list,:] ----------
__global__ __launch_bounds__(256) void spmm_k(const int* __restrict__ list,
                                              const float* __restrict__ val,
                                              const int* __restrict__ cnt,
                                              const float* __restrict__ src,
                                              float* __restrict__ dst) {
    int i = blockIdx.x;
    int f2 = threadIdx.x;
    int c = cnt[i];
    float ssum = 0.f;
    for (int t = 0; t < c; ++t) ssum += fabsf(val[(size_t)i * CAP + t]);
    float acc0 = 0.f, acc1 = 0.f;
    for (int t = 0; t < c; ++t) {
        int j = list[(size_t)i * CAP + t];
        float a = val[(size_t)i * CAP + t];
        float2 s = *(const float2*)&src[(size_t)j * OUT_FT + f2 * 2];
        acc0 += a * s.x;
        acc1 += a * s.y;
    }
    float sc = 1.0f / fmaxf(ssum, EPSN);
    float2 o = make_float2(acc0 * sc, acc1 * sc);
    *(float2*)&dst[(size_t)i * OUT_FT + f2 * 2] = o;
}

extern "C" void kernel_launch(void* const* d_in, const int* in_sizes, int n_in,
                              void* d_out, int out_size, void* d_ws, size_t ws_size,
                              hipStream_t stream) {
    const float* x      = (const float*)d_in[0];   // [4096,512]
    const float* Hmat   = (const float*)d_in[1];   // [4096,4096]
    const float* proj_w = (const float*)d_in[2];   // [512,512]
    const float* proj_b = (const float*)d_in[3];   // [512]
    const float* w1     = (const float*)d_in[4];   // [4096,4096]
    const float* w2     = (const float*)d_in[5];   // [4096,4096]
    float* out = (float*)d_out;

    char* ws = (char*)d_ws;
    unsigned short* xnh   = (unsigned short*)(ws + 0);         // 4 MB
    unsigned short* xnl   = (unsigned short*)(ws + 4194304);   // 4 MB
    float*          cosm  = (float*)(ws + 8388608);            // 64 MB, dead after topk_fb
    int*            elist = (int*)  (ws + 8388608);            // 4 MB (aliases dead cos)
    float*          eval_ = (float*)(ws + 12582912);           // 4 MB (aliases dead cos)
    float*          h     = (float*)(ws + 25165824);           // 8 MB (aliases dead cos)
    float*          h2    = (float*)(ws + 33554432);           // 8 MB (aliases dead cos)
    unsigned short* whi   = (unsigned short*)(ws + 50331648);  // 512 KB (aliases dead cos)
    unsigned short* wlo   = (unsigned short*)(ws + 50855936);  // 512 KB (aliases dead cos)
    int*            cnt16 = (int*)(ws + 52428800);             // 256 KB (aliases dead cos)
    unsigned*       maskT = (unsigned*)(ws + 75497472);        // 2 MB
    int*            ecnt    = (int*)(ws + 77594624);           // 16 KB
    int*            rcnt    = (int*)(ws + 77611008);           // 16 KB
    float*          norminv = (float*)(ws + 77627392);         // 16 KB
    float*          nrm     = (float*)(ws + 77643776);         // 16 KB
    int*            fbflag  = (int*)(ws + 77660160);           // 16 KB
    int*            rlist   = (int*)(ws + 77692928);           // 4 MB
    float*          rval    = (float*)(ws + 81887232);         // 4 MB
    unsigned*       cbits   = (unsigned*)(ws + 86081536);      // 2 MB [4096][128]

    // 1. norms + bf16 hi/lo of xn; zero fallback flags
    rownorm_k<<<N, 256, 0, stream>>>(x, xnh, xnl, norminv, nrm, fbflag);
    // 2. approx cos: upper-tri MFMA + mirror + exclusive bitmask emission
    cos_gemm_k<<<CNB * (CNB + 1) / 2, 256, 0, stream>>>(xnh, xnl, cosm, cbits);
    // 3. fast top-k from bitmask + gathered values (fbflag on guard break)
    topk_fast_k<<<N, 256, 0, stream>>>(cbits, cosm, x, norminv, maskT,
                                       w2, Hmat, rlist, rval, rcnt, fbflag);
    // 4. fallback rows: r15 full path from dense cos (before cos dies)
    topk_fb_k<<<N, 256, 0, stream>>>(fbflag, cosm, x, norminv, maskT,
                                     w2, Hmat, rlist, rval, rcnt);
    // 5. h = nrm*(xn @ proj_w^T) + b (cos region now dead; h aliases it)
    cast_w_k<<<256, 256, 0, stream>>>(proj_w, whi, wlo);
    proj_mfma_k<<<dim3(OUT_FT / 64, N / 64), 256, 0, stream>>>(xnh, xnl, whi, wlo,
                                                               proj_b, nrm, h);
    // 6. column lists: count -> fill at prefix offsets
    count_cols_k<<<dim3(16, 16), 256, 0, stream>>>(maskT, cnt16);
    fill_cols_k<<<dim3(16, 16), 256, 0, stream>>>(maskT, cnt16, w1, Hmat, elist, eval_, ecnt);
    // 7. h2[e,:] = normalize . gather-sum over column lists
    spmm_k<<<N, 256, 0, stream>>>(elist, eval_, ecnt, h, h2);
    // 8. out[v,:] = normalize . gather-sum over row lists
    spmm_k<<<N, 256, 0, stream>>>(rlist, rval, rcnt, h2, out);
}